// Round 1
// baseline (2257.659 us; speedup 1.0000x reference)
//
#include <hip/hip_runtime.h>
#include <hip/hip_bf16.h>

// EarthSpecificBlock (Pangu-style 3D window attention), MI355X baseline.
// Shapes fixed: Z=8,H=96,W=180, DIM=192, HEADS=6, hd=32, WIN=(2,6,12),
// nZ=4,nH=16,nW=15 -> 960 windows x 144 tokens. fp32 in/out, bf16 ws.

typedef __hip_bfloat16 bf16;

#define QKV_PART 26542080   // 960*6*144*32 elements per q/k/v part
#define NTOK 138240

// window (iw, n) -> merged token index
__device__ __forceinline__ int token_of(int iw, int n) {
    int wi = iw % 15, hi = (iw / 15) % 16, zi = iw / 240;
    int ww = n % 12, hh = (n / 12) % 6, zz = n / 72;
    return ((zi * 2 + zz) * 96 + hi * 6 + hh) * 180 + wi * 12 + ww;
}

// bias_r[th][i][j] = bias_table[posidx(i,j)][t][h],  th = t*6+h  (bf16, 64*6*144*144)
__global__ __launch_bounds__(256) void bias_reorg(const float* __restrict__ bias_table,
                                                  bf16* __restrict__ bias_r) {
    int id = blockIdx.x * 256 + threadIdx.x;       // 144*144*384 = 7,962,624
    if (id >= 144 * 144 * 384) return;
    int th = id % 384;
    int pair = id / 384;                           // i*144 + j
    int i = pair / 144, j = pair % 144;
    int z1 = i / 72, h1 = (i / 12) % 6, w1 = i % 12;
    int z2 = j / 72, h2 = (j / 12) % 6, w2 = j % 12;
    int idx = (z1 + 2 * z2) * 828 + (h1 + 6 * h2) * 23 + (w1 - w2 + 11);
    bias_r[(size_t)th * 20736 + pair] = __float2bfloat16(bias_table[idx * 384 + th]);
}

// QKV GEMM: per (window, 48-row chunk, part in {q,k,v}); A gathered via window map.
// out layout per part: [iw][head][n][d] bf16
__global__ __launch_bounds__(256) void qkv_kernel(const float* __restrict__ x,
                                                  const float* __restrict__ w_qkv,
                                                  const float* __restrict__ b_qkv,
                                                  bf16* __restrict__ qkv_ws) {
    __shared__ float As[48][192];
    __shared__ float Bs[32][192];
    int iw = blockIdx.x, rc = blockIdx.y, part = blockIdx.z;
    int tid = threadIdx.x;
    for (int e = tid; e < 48 * 192; e += 256) {
        int r = e / 192, c = e - r * 192;
        As[r][c] = x[(size_t)token_of(iw, rc * 48 + r) * 192 + c];
    }
    int tn = tid & 31, ti = tid >> 5;
    float acc[6][6];
#pragma unroll
    for (int a = 0; a < 6; ++a)
#pragma unroll
        for (int b = 0; b < 6; ++b) acc[a][b] = 0.f;

    for (int k0 = 0; k0 < 192; k0 += 32) {
        __syncthreads();
        for (int e = tid; e < 32 * 192; e += 256) {
            int kk = e / 192, n = e - kk * 192;
            Bs[kk][n] = w_qkv[(size_t)(k0 + kk) * 576 + part * 192 + n];
        }
        __syncthreads();
        for (int kk = 0; kk < 32; ++kk) {
            float bv[6], av[6];
#pragma unroll
            for (int c2 = 0; c2 < 6; ++c2) bv[c2] = Bs[kk][tn + 32 * c2];
#pragma unroll
            for (int rr = 0; rr < 6; ++rr) av[rr] = As[ti + 8 * rr][k0 + kk];
#pragma unroll
            for (int rr = 0; rr < 6; ++rr)
#pragma unroll
                for (int c2 = 0; c2 < 6; ++c2) acc[rr][c2] += av[rr] * bv[c2];
        }
    }
    bf16* outp = qkv_ws + (size_t)part * QKV_PART;
#pragma unroll
    for (int rr = 0; rr < 6; ++rr) {
        int row = rc * 48 + ti + 8 * rr;
#pragma unroll
        for (int c2 = 0; c2 < 6; ++c2) {
            int n = tn + 32 * c2;                       // head = c2, d = tn
            float v = acc[rr][c2] + b_qkv[part * 192 + n];
            outp[(((size_t)iw * 6 + c2) * 144 + row) * 32 + tn] = __float2bfloat16(v);
        }
    }
}

// Attention: per (window, head, 36-query chunk). S=QK^T/sqrt(32)+bias, softmax, O=S*V.
__global__ __launch_bounds__(256) void attn_kernel(const bf16* __restrict__ qkv_ws,
                                                   const bf16* __restrict__ bias_r,
                                                   bf16* __restrict__ o_ws) {
    __shared__ float Kt[144][33];   // padded: S-compute reads stride-33 -> conflict-free
    __shared__ float Vt[144][32];
    __shared__ float Qt[36][32];
    __shared__ float S[36][144];
    int iw = blockIdx.x, h = blockIdx.y, qc = blockIdx.z;
    int tid = threadIdx.x;
    const bf16* qp = qkv_ws + ((size_t)iw * 6 + h) * 4608;
    const bf16* kp = qp + QKV_PART;
    const bf16* vp = qp + 2 * (size_t)QKV_PART;
    for (int e = tid; e < 144 * 32; e += 256) {
        int r = e >> 5, d = e & 31;
        Kt[r][d] = __bfloat162float(kp[e]);
        Vt[r][d] = __bfloat162float(vp[e]);
    }
    for (int e = tid; e < 36 * 32; e += 256)
        Qt[e >> 5][e & 31] = __bfloat162float(qp[qc * 1152 + e]);
    __syncthreads();

    const bf16* bp = bias_r + ((size_t)((iw & 63) * 6 + h)) * 20736 + qc * 36 * 144;
    const float inv_scale = 0.17677669529663687f;   // 1/sqrt(32)
    for (int e = tid; e < 36 * 144; e += 256) {
        int i = e / 144, j = e - i * 144;
        float s = 0.f;
#pragma unroll
        for (int d = 0; d < 32; ++d) s += Qt[i][d] * Kt[j][d];
        S[i][j] = s * inv_scale + __bfloat162float(bp[e]);
    }
    __syncthreads();

    int lane = tid & 63, wv = tid >> 6;
    for (int i = wv; i < 36; i += 4) {
        float v0 = S[i][lane];
        float v1 = S[i][lane + 64];
        float v2 = (lane < 16) ? S[i][lane + 128] : -1e30f;
        float m = fmaxf(fmaxf(v0, v1), v2);
#pragma unroll
        for (int off = 32; off; off >>= 1) m = fmaxf(m, __shfl_xor(m, off));
        float e0 = __expf(v0 - m), e1 = __expf(v1 - m);
        float e2 = (lane < 16) ? __expf(v2 - m) : 0.f;
        float ssum = e0 + e1 + e2;
#pragma unroll
        for (int off = 32; off; off >>= 1) ssum += __shfl_xor(ssum, off);
        float inv = 1.f / ssum;
        S[i][lane] = e0 * inv;
        S[i][lane + 64] = e1 * inv;
        if (lane < 16) S[i][lane + 128] = e2 * inv;
    }
    __syncthreads();

    for (int e = tid; e < 36 * 32; e += 256) {
        int i = e >> 5, d = e & 31;
        float s = 0.f;
        for (int j = 0; j < 144; ++j) s += S[i][j] * Vt[j][d];
        int t = token_of(iw, qc * 36 + i);
        o_ws[(size_t)t * 192 + h * 32 + d] = __float2bfloat16(s);
    }
}

// Fused: P = O@w_proj + b_proj ; x1 = x + LN(P,g1,b1) ; Q = x1@w_mlp + b_mlp ;
//        out = x1 + LN(Q,g2,b2).  32 token rows per block.
__global__ __launch_bounds__(256) void mlp_kernel(const bf16* __restrict__ o_ws,
                                                  const float* __restrict__ x,
                                                  const float* __restrict__ w_proj,
                                                  const float* __restrict__ b_proj,
                                                  const float* __restrict__ g1,
                                                  const float* __restrict__ b1,
                                                  const float* __restrict__ g2,
                                                  const float* __restrict__ b2,
                                                  const float* __restrict__ w_mlp,
                                                  const float* __restrict__ b_mlp,
                                                  float* __restrict__ out) {
    __shared__ float As[32][192];
    __shared__ float Bs[32][192];
    int t0 = blockIdx.x * 32;
    int tid = threadIdx.x, tn = tid & 31, ti = tid >> 5;

    for (int e = tid; e < 32 * 192; e += 256) {
        int r = e / 192, c = e - r * 192;
        As[r][c] = __bfloat162float(o_ws[(size_t)(t0 + r) * 192 + c]);
    }
    float acc[4][6];
#pragma unroll
    for (int a = 0; a < 4; ++a)
#pragma unroll
        for (int b = 0; b < 6; ++b) acc[a][b] = 0.f;

    for (int k0 = 0; k0 < 192; k0 += 32) {
        __syncthreads();
        for (int e = tid; e < 32 * 192; e += 256) {
            int kk = e / 192, n = e - kk * 192;
            Bs[kk][n] = w_proj[(size_t)(k0 + kk) * 192 + n];
        }
        __syncthreads();
        for (int kk = 0; kk < 32; ++kk) {
            float bv[6], av[4];
#pragma unroll
            for (int c2 = 0; c2 < 6; ++c2) bv[c2] = Bs[kk][tn + 32 * c2];
#pragma unroll
            for (int rr = 0; rr < 4; ++rr) av[rr] = As[ti + 8 * rr][k0 + kk];
#pragma unroll
            for (int rr = 0; rr < 4; ++rr)
#pragma unroll
                for (int c2 = 0; c2 < 6; ++c2) acc[rr][c2] += av[rr] * bv[c2];
        }
    }

    // LN1 + residual (row r is held by the 32 consecutive lanes with ti = r%8)
    float x1v[4][6];
#pragma unroll
    for (int rr = 0; rr < 4; ++rr) {
        int r = ti + 8 * rr;
        float pv[6];
#pragma unroll
        for (int c2 = 0; c2 < 6; ++c2) pv[c2] = acc[rr][c2] + b_proj[tn + 32 * c2];
        float s1 = pv[0] + pv[1] + pv[2] + pv[3] + pv[4] + pv[5];
#pragma unroll
        for (int off = 16; off; off >>= 1) s1 += __shfl_xor(s1, off, 32);
        float mean = s1 * (1.f / 192.f);
        float s2 = 0.f;
#pragma unroll
        for (int c2 = 0; c2 < 6; ++c2) { float d = pv[c2] - mean; s2 += d * d; }
#pragma unroll
        for (int off = 16; off; off >>= 1) s2 += __shfl_xor(s2, off, 32);
        float rstd = rsqrtf(s2 * (1.f / 192.f) + 1e-5f);
#pragma unroll
        for (int c2 = 0; c2 < 6; ++c2) {
            int n = tn + 32 * c2;
            float ln = (pv[c2] - mean) * rstd * g1[n] + b1[n];
            x1v[rr][c2] = x[(size_t)(t0 + r) * 192 + n] + ln;
        }
    }
    __syncthreads();
#pragma unroll
    for (int rr = 0; rr < 4; ++rr)
#pragma unroll
        for (int c2 = 0; c2 < 6; ++c2) As[ti + 8 * rr][tn + 32 * c2] = x1v[rr][c2];

    float acc2[4][6];
#pragma unroll
    for (int a = 0; a < 4; ++a)
#pragma unroll
        for (int b = 0; b < 6; ++b) acc2[a][b] = 0.f;

    for (int k0 = 0; k0 < 192; k0 += 32) {
        __syncthreads();
        for (int e = tid; e < 32 * 192; e += 256) {
            int kk = e / 192, n = e - kk * 192;
            Bs[kk][n] = w_mlp[(size_t)(k0 + kk) * 192 + n];
        }
        __syncthreads();
        for (int kk = 0; kk < 32; ++kk) {
            float bv[6], av[4];
#pragma unroll
            for (int c2 = 0; c2 < 6; ++c2) bv[c2] = Bs[kk][tn + 32 * c2];
#pragma unroll
            for (int rr = 0; rr < 4; ++rr) av[rr] = As[ti + 8 * rr][k0 + kk];
#pragma unroll
            for (int rr = 0; rr < 4; ++rr)
#pragma unroll
                for (int c2 = 0; c2 < 6; ++c2) acc2[rr][c2] += av[rr] * bv[c2];
        }
    }

    // LN2 + residual -> out
#pragma unroll
    for (int rr = 0; rr < 4; ++rr) {
        int r = ti + 8 * rr;
        float pv[6];
#pragma unroll
        for (int c2 = 0; c2 < 6; ++c2) pv[c2] = acc2[rr][c2] + b_mlp[tn + 32 * c2];
        float s1 = pv[0] + pv[1] + pv[2] + pv[3] + pv[4] + pv[5];
#pragma unroll
        for (int off = 16; off; off >>= 1) s1 += __shfl_xor(s1, off, 32);
        float mean = s1 * (1.f / 192.f);
        float s2 = 0.f;
#pragma unroll
        for (int c2 = 0; c2 < 6; ++c2) { float d = pv[c2] - mean; s2 += d * d; }
#pragma unroll
        for (int off = 16; off; off >>= 1) s2 += __shfl_xor(s2, off, 32);
        float rstd = rsqrtf(s2 * (1.f / 192.f) + 1e-5f);
#pragma unroll
        for (int c2 = 0; c2 < 6; ++c2) {
            int n = tn + 32 * c2;
            float ln = (pv[c2] - mean) * rstd * g2[n] + b2[n];
            out[(size_t)(t0 + r) * 192 + n] = x1v[rr][c2] + ln;
        }
    }
}

extern "C" void kernel_launch(void* const* d_in, const int* in_sizes, int n_in,
                              void* d_out, int out_size, void* d_ws, size_t ws_size,
                              hipStream_t stream) {
    const float* x          = (const float*)d_in[0];
    const float* w_qkv      = (const float*)d_in[1];
    const float* b_qkv      = (const float*)d_in[2];
    const float* w_proj     = (const float*)d_in[3];
    const float* b_proj     = (const float*)d_in[4];
    const float* bias_table = (const float*)d_in[5];
    const float* g1         = (const float*)d_in[6];
    const float* b1         = (const float*)d_in[7];
    const float* g2         = (const float*)d_in[8];
    const float* b2         = (const float*)d_in[9];
    const float* w_mlp      = (const float*)d_in[10];
    const float* b_mlp      = (const float*)d_in[11];

    char* ws = (char*)d_ws;
    bf16* qkv_ws = (bf16*)ws;                           // 3 * 26,542,080 bf16 = 159,252,480 B
    bf16* bias_r = (bf16*)(ws + 159252480);             // 7,962,624 bf16  = 15,925,248 B
    bf16* o_ws   = (bf16*)(ws + 175177728);             // 26,542,080 bf16 = 53,084,160 B
    // total ws use: 228,261,888 B

    hipLaunchKernelGGL(bias_reorg, dim3(31104), dim3(256), 0, stream, bias_table, bias_r);
    hipLaunchKernelGGL(qkv_kernel, dim3(960, 3, 3), dim3(256), 0, stream, x, w_qkv, b_qkv, qkv_ws);
    hipLaunchKernelGGL(attn_kernel, dim3(960, 6, 4), dim3(256), 0, stream, qkv_ws, bias_r, o_ws);
    hipLaunchKernelGGL(mlp_kernel, dim3(4320), dim3(256), 0, stream,
                       o_ws, x, w_proj, b_proj, g1, b1, g2, b2, w_mlp, b_mlp, (float*)d_out);
}

// Round 2
// 563.883 us; speedup vs baseline: 4.0038x; 4.0038x over previous
//
#include <hip/hip_runtime.h>

// EarthSpecificBlock, MI355X round 2: all matmuls on bf16 MFMA 16x16x32.
// Shapes: 960 windows x 144 tok, DIM=192, 6 heads x 32, fp32 in/out.

#define QKV_PART 26542080   // 960*6*144*32 elements per q/k/v part

typedef __attribute__((ext_vector_type(8))) short bfrag;          // 8 bf16 (4 VGPR)
typedef __attribute__((ext_vector_type(4))) float f32x4;          // C/D frag
typedef __attribute__((ext_vector_type(4))) unsigned short us4;   // 8B of bf16

__device__ __forceinline__ unsigned short f2bf(float f) {
    unsigned int u = __builtin_bit_cast(unsigned int, f);
    u += 0x7fffu + ((u >> 16) & 1u);        // RNE
    return (unsigned short)(u >> 16);
}
__device__ __forceinline__ float bf2f(unsigned short s) {
    return __builtin_bit_cast(float, ((unsigned int)s) << 16);
}
__device__ __forceinline__ int token_of(int iw, int n) {
    int wi = iw % 15, hi = (iw / 15) % 16, zi = iw / 240;
    int ww = n % 12, hh = (n / 12) % 6, zz = n / 72;
    return ((zi * 2 + zz) * 96 + hi * 6 + hh) * 180 + wi * 12 + ww;
}

// ---- setup: transpose+convert w_qkv [192][576] -> [576][192] bf16 ----
__global__ __launch_bounds__(256) void wconv(const float* __restrict__ w_qkv,
                                             unsigned short* __restrict__ wt) {
    int id = blockIdx.x * 256 + threadIdx.x;       // 110592
    if (id >= 110592) return;
    int k = id / 576, c = id - k * 576;
    wt[c * 192 + k] = f2bf(w_qkv[id]);
}

// ---- bias_r[th][i][j] = bias_table[posidx(i,j)][t][h] (bf16) ----
__global__ __launch_bounds__(256) void bias_reorg(const float* __restrict__ bias_table,
                                                  unsigned short* __restrict__ bias_r) {
    int id = blockIdx.x * 256 + threadIdx.x;       // 144*144*384
    if (id >= 144 * 144 * 384) return;
    int th = id % 384;
    int pair = id / 384;
    int i = pair / 144, j = pair % 144;
    int z1 = i / 72, h1 = (i / 12) % 6, w1 = i % 12;
    int z2 = j / 72, h2 = (j / 12) % 6, w2 = j % 12;
    int idx = (z1 + 2 * z2) * 828 + (h1 + 6 * h2) * 23 + (w1 - w2 + 11);
    bias_r[(size_t)th * 20736 + pair] = f2bf(bias_table[idx * 384 + th]);
}

// ---- QKV GEMM: M=138240 (64/block), N=576, K=192. out [part][iw][h][n][32] bf16 ----
__global__ __launch_bounds__(256) void qkv_mfma(const float* __restrict__ x,
                                                const unsigned short* __restrict__ wt,
                                                const float* __restrict__ b_qkv,
                                                unsigned short* __restrict__ qkv_ws) {
    __shared__ __align__(16) unsigned short As[64 * 40];    //  5120 B, pad-40
    __shared__ __align__(16) unsigned short Bs[576 * 40];   // 46080 B
    int tid = threadIdx.x;
    int m0 = blockIdx.x * 64;
    int w = tid >> 6, l = tid & 63, li = l & 15, lg = l >> 4;

    f32x4 acc[36];
#pragma unroll
    for (int nt = 0; nt < 36; ++nt) acc[nt] = (f32x4){0.f, 0.f, 0.f, 0.f};

    for (int kk = 0; kk < 6; ++kk) {
        __syncthreads();
        // stage A: 64 rows x 32 k (fp32 -> bf16)
#pragma unroll
        for (int i = 0; i < 2; ++i) {
            int idx = tid + i * 256;                 // < 512
            int r = idx >> 3, g = idx & 7;
            float4 v = *(const float4*)&x[(size_t)(m0 + r) * 192 + kk * 32 + g * 4];
            us4 p; p[0] = f2bf(v.x); p[1] = f2bf(v.y); p[2] = f2bf(v.z); p[3] = f2bf(v.w);
            *(us4*)&As[r * 40 + g * 4] = p;
        }
        // stage B: 576 rows x 32 k from wt [576][192]
#pragma unroll
        for (int i = 0; i < 9; ++i) {
            int idx = tid + i * 256;                 // < 2304
            int r = idx >> 2, g = idx & 3;
            *(uint4*)&Bs[r * 40 + g * 8] = *(const uint4*)&wt[(size_t)r * 192 + kk * 32 + g * 8];
        }
        __syncthreads();
        bfrag a = *(const bfrag*)&As[(w * 16 + li) * 40 + lg * 8];
#pragma unroll
        for (int nt = 0; nt < 36; ++nt) {
            bfrag b = *(const bfrag*)&Bs[(nt * 16 + li) * 40 + lg * 8];
            acc[nt] = __builtin_amdgcn_mfma_f32_16x16x32_bf16(a, b, acc[nt], 0, 0, 0);
        }
    }

    // epilogue: token -> (iw, n) bases for this lane's 4 rows
    int base[4];
#pragma unroll
    for (int r = 0; r < 4; ++r) {
        int t = m0 + w * 16 + lg * 4 + r;
        int z = t / 17280; int r1 = t - z * 17280;
        int hh_ = r1 / 180;  int ww_ = r1 - hh_ * 180;
        int zi = z >> 1, zz = z & 1;
        int hi = hh_ / 6, hs = hh_ - hi * 6;
        int wi = ww_ / 12, wsm = ww_ - wi * 12;
        int iw = (zi * 16 + hi) * 15 + wi;
        int n = (zz * 6 + hs) * 12 + wsm;
        base[r] = iw * 27648 + n * 32;
    }
#pragma unroll
    for (int nt = 0; nt < 36; ++nt) {
        int f0 = nt * 16;
        int part = f0 / 192;
        int fr = f0 - part * 192;
        int h = fr >> 5, d0 = fr & 31;
        float bias = b_qkv[f0 + li];
        size_t off = (size_t)part * QKV_PART + h * 4608 + d0 + li;
#pragma unroll
        for (int r = 0; r < 4; ++r)
            qkv_ws[off + base[r]] = f2bf(acc[nt][r] + bias);
    }
}

// ---- Attention: block=(iw,h), 3 waves x 3 query-tiles. S^T = mfma(K,Q). ----
__global__ __launch_bounds__(192) void attn_mfma(const unsigned short* __restrict__ qkv_ws,
                                                 const unsigned short* __restrict__ bias_r,
                                                 unsigned short* __restrict__ o_ws) {
    __shared__ __align__(16) unsigned short Kl[144 * 40];   // 11520 B
    __shared__ __align__(16) unsigned short Ql[144 * 40];   // 11520 B
    __shared__ __align__(16) unsigned short Vt[32 * 168];   // 10752 B (V^T, k-padded to 160)
    __shared__ __align__(16) unsigned short Pb[3][48 * 40]; // 11520 B per-wave P/O buf
    int tid = threadIdx.x;
    int iw = blockIdx.x, h = blockIdx.y;
    int w = tid >> 6, l = tid & 63, li = l & 15, lg = l >> 4;

    const unsigned short* qp = qkv_ws + (size_t)(iw * 6 + h) * 4608;
    const unsigned short* kp = qp + (size_t)QKV_PART;
    const unsigned short* vp = qp + 2 * (size_t)QKV_PART;

    // stage K, Q ([144][40] padded), V transposed ([32][168], cols 144..159 zeroed)
#pragma unroll
    for (int i = 0; i < 3; ++i) {
        int idx = tid + i * 192;                    // exactly 576
        int r = idx >> 2, g = idx & 3;
        *(uint4*)&Kl[r * 40 + g * 8] = *(const uint4*)&kp[r * 32 + g * 8];
        *(uint4*)&Ql[r * 40 + g * 8] = *(const uint4*)&qp[r * 32 + g * 8];
        uint4 v = *(const uint4*)&vp[r * 32 + g * 8];
        unsigned int vv[4] = {v.x, v.y, v.z, v.w};
#pragma unroll
        for (int e = 0; e < 4; ++e) {
            Vt[(g * 8 + 2 * e + 0) * 168 + r] = (unsigned short)(vv[e] & 0xffffu);
            Vt[(g * 8 + 2 * e + 1) * 168 + r] = (unsigned short)(vv[e] >> 16);
        }
    }
    if (tid < 64) {
        int d = tid >> 1, half = tid & 1;
        *(uint4*)&Vt[d * 168 + 144 + half * 8] = (uint4){0u, 0u, 0u, 0u};
    }
    __syncthreads();

    int it0 = w * 3;   // wave's 3 query tiles
    // Q fragments
    bfrag qf[3];
#pragma unroll
    for (int itl = 0; itl < 3; ++itl)
        qf[itl] = *(const bfrag*)&Ql[((it0 + itl) * 16 + li) * 40 + lg * 8];

    // S^T[j][i] = sum_d K[j][d] Q[i][d]
    f32x4 S[9][3];
#pragma unroll
    for (int jt = 0; jt < 9; ++jt) {
        bfrag kf = *(const bfrag*)&Kl[(jt * 16 + li) * 40 + lg * 8];
#pragma unroll
        for (int itl = 0; itl < 3; ++itl) {
            f32x4 z = (f32x4){0.f, 0.f, 0.f, 0.f};
            S[jt][itl] = __builtin_amdgcn_mfma_f32_16x16x32_bf16(kf, qf[itl], z, 0, 0, 0);
        }
    }

    // scale + bias: lane holds (j = jt*16+lg*4+r, i = (it0+itl)*16+li)
    const unsigned short* bp = bias_r + ((size_t)((iw & 63) * 6 + h)) * 20736;
    const float inv_scale = 0.17677669529663687f;   // 1/sqrt(32)
#pragma unroll
    for (int jt = 0; jt < 9; ++jt) {
#pragma unroll
        for (int itl = 0; itl < 3; ++itl) {
            int i = (it0 + itl) * 16 + li;
            int j0 = jt * 16 + lg * 4;
            us4 bv = *(const us4*)&bp[i * 144 + j0];
#pragma unroll
            for (int r = 0; r < 4; ++r)
                S[jt][itl][r] = S[jt][itl][r] * inv_scale + bf2f(bv[r]);
        }
    }

    // softmax over j (per-lane 36 + shfl_xor 16,32); keep P unnormalized, defer 1/sum
    float inv[3];
#pragma unroll
    for (int itl = 0; itl < 3; ++itl) {
        float mx = -3.0e38f;
#pragma unroll
        for (int jt = 0; jt < 9; ++jt)
#pragma unroll
            for (int r = 0; r < 4; ++r) mx = fmaxf(mx, S[jt][itl][r]);
        mx = fmaxf(mx, __shfl_xor(mx, 16));
        mx = fmaxf(mx, __shfl_xor(mx, 32));
        float sum = 0.f;
#pragma unroll
        for (int jt = 0; jt < 9; ++jt)
#pragma unroll
            for (int r = 0; r < 4; ++r) {
                float e = __expf(S[jt][itl][r] - mx);
                S[jt][itl][r] = e;
                sum += e;
            }
        sum += __shfl_xor(sum, 16);
        sum += __shfl_xor(sum, 32);
        inv[itl] = 1.f / sum;
    }

    // PV: O^T[d][i] += V^T[d][jc*32..] * P^T[jc*32..][i], 5 chunks (j padded to 160)
    f32x4 O[2][3];
#pragma unroll
    for (int dt = 0; dt < 2; ++dt)
#pragma unroll
        for (int itl = 0; itl < 3; ++itl) O[dt][itl] = (f32x4){0.f, 0.f, 0.f, 0.f};

    for (int jc = 0; jc < 5; ++jc) {
#pragma unroll
        for (int itl = 0; itl < 3; ++itl) {
            int irow = itl * 16 + li;
#pragma unroll
            for (int half = 0; half < 2; ++half) {
                int jt = jc * 2 + half;
                us4 pk;
                if (jt < 9) {
                    pk[0] = f2bf(S[jt][itl][0]); pk[1] = f2bf(S[jt][itl][1]);
                    pk[2] = f2bf(S[jt][itl][2]); pk[3] = f2bf(S[jt][itl][3]);
                } else {
                    pk = (us4){0, 0, 0, 0};
                }
                *(us4*)&Pb[w][irow * 40 + half * 16 + lg * 4] = pk;
            }
        }
        bfrag pf[3], af[2];
#pragma unroll
        for (int itl = 0; itl < 3; ++itl)
            pf[itl] = *(const bfrag*)&Pb[w][(itl * 16 + li) * 40 + lg * 8];
#pragma unroll
        for (int dt = 0; dt < 2; ++dt)
            af[dt] = *(const bfrag*)&Vt[(dt * 16 + li) * 168 + jc * 32 + lg * 8];
#pragma unroll
        for (int dt = 0; dt < 2; ++dt)
#pragma unroll
            for (int itl = 0; itl < 3; ++itl)
                O[dt][itl] = __builtin_amdgcn_mfma_f32_16x16x32_bf16(af[dt], pf[itl], O[dt][itl], 0, 0, 0);
    }

    // normalize + transpose via Pb, then coalesced global write (64B per token row)
#pragma unroll
    for (int itl = 0; itl < 3; ++itl) {
#pragma unroll
        for (int dt = 0; dt < 2; ++dt) {
            us4 ov;
            ov[0] = f2bf(O[dt][itl][0] * inv[itl]);
            ov[1] = f2bf(O[dt][itl][1] * inv[itl]);
            ov[2] = f2bf(O[dt][itl][2] * inv[itl]);
            ov[3] = f2bf(O[dt][itl][3] * inv[itl]);
            *(us4*)&Pb[w][(itl * 16 + li) * 40 + dt * 16 + lg * 4] = ov;
        }
    }
#pragma unroll
    for (int s = 0; s < 3; ++s) {
        int gi = s * 64 + l;                  // < 192
        int row = gi >> 2, g = gi & 3;
        uint4 v = *(const uint4*)&Pb[w][row * 40 + g * 8];
        int t = token_of(iw, it0 * 16 + row);
        *(uint4*)&o_ws[(size_t)t * 192 + h * 32 + g * 8] = v;
    }
}

// ---- Fused proj+LN1+res -> mlp+LN2+res. 64 rows/block, MFMA GEMMs. ----
__global__ __launch_bounds__(256) void mlp_mfma(const unsigned short* __restrict__ o_ws,
                                                const float* __restrict__ x,
                                                const float* __restrict__ w_proj,
                                                const float* __restrict__ b_proj,
                                                const float* __restrict__ g1,
                                                const float* __restrict__ b1,
                                                const float* __restrict__ g2,
                                                const float* __restrict__ b2,
                                                const float* __restrict__ w_mlp,
                                                const float* __restrict__ b_mlp,
                                                float* __restrict__ out) {
    __shared__ __align__(16) unsigned short Al[64 * 200];   // 25600 B (A1 then x1)
    __shared__ __align__(16) unsigned short Bl[192 * 40];   // 15360 B
    int tid = threadIdx.x;
    int t0 = blockIdx.x * 64;
    int w = tid >> 6, l = tid & 63, li = l & 15, lg = l >> 4;

    // stage A1 = o_ws rows (bf16, full K)
#pragma unroll
    for (int i = 0; i < 6; ++i) {
        int idx = tid + i * 256;                 // < 1536
        int r = idx / 24, g = idx - r * 24;
        *(uint4*)&Al[r * 200 + g * 8] = *(const uint4*)&o_ws[(size_t)(t0 + r) * 192 + g * 8];
    }
    __syncthreads();

    f32x4 C[12];
#pragma unroll
    for (int nt = 0; nt < 12; ++nt) C[nt] = (f32x4){0.f, 0.f, 0.f, 0.f};
    for (int kk = 0; kk < 6; ++kk) {
        __syncthreads();
#pragma unroll
        for (int i = 0; i < 6; ++i) {
            int idx = tid + i * 256;             // < 1536
            int kr = idx / 48, g = idx - kr * 48;
            float4 v = *(const float4*)&w_proj[(size_t)(kk * 32 + kr) * 192 + g * 4];
            Bl[(g * 4 + 0) * 40 + kr] = f2bf(v.x);
            Bl[(g * 4 + 1) * 40 + kr] = f2bf(v.y);
            Bl[(g * 4 + 2) * 40 + kr] = f2bf(v.z);
            Bl[(g * 4 + 3) * 40 + kr] = f2bf(v.w);
        }
        __syncthreads();
        bfrag a = *(const bfrag*)&Al[(w * 16 + li) * 200 + kk * 32 + lg * 8];
#pragma unroll
        for (int nt = 0; nt < 12; ++nt) {
            bfrag b = *(const bfrag*)&Bl[(nt * 16 + li) * 40 + lg * 8];
            C[nt] = __builtin_amdgcn_mfma_f32_16x16x32_bf16(a, b, C[nt], 0, 0, 0);
        }
    }

    // LN1 + residual; C := x1 (f32); write bf16 x1 into Al (own rows only)
    {
        float bp[12], gg[12], bb[12];
#pragma unroll
        for (int nt = 0; nt < 12; ++nt) {
            int f = nt * 16 + li;
            bp[nt] = b_proj[f]; gg[nt] = g1[f]; bb[nt] = b1[f];
        }
#pragma unroll
        for (int r = 0; r < 4; ++r) {
            float s1 = 0.f;
#pragma unroll
            for (int nt = 0; nt < 12; ++nt) s1 += C[nt][r] + bp[nt];
            s1 += __shfl_xor(s1, 1); s1 += __shfl_xor(s1, 2);
            s1 += __shfl_xor(s1, 4); s1 += __shfl_xor(s1, 8);
            float mean = s1 * (1.f / 192.f);
            float s2 = 0.f;
#pragma unroll
            for (int nt = 0; nt < 12; ++nt) {
                float dv = C[nt][r] + bp[nt] - mean; s2 += dv * dv;
            }
            s2 += __shfl_xor(s2, 1); s2 += __shfl_xor(s2, 2);
            s2 += __shfl_xor(s2, 4); s2 += __shfl_xor(s2, 8);
            float rstd = rsqrtf(s2 * (1.f / 192.f) + 1e-5f);
            int row = w * 16 + lg * 4 + r;
            int t = t0 + row;
#pragma unroll
            for (int nt = 0; nt < 12; ++nt) {
                int f = nt * 16 + li;
                float ln = (C[nt][r] + bp[nt] - mean) * rstd * gg[nt] + bb[nt];
                float x1 = x[(size_t)t * 192 + f] + ln;
                C[nt][r] = x1;
                Al[row * 200 + f] = f2bf(x1);
            }
        }
    }

    // GEMM2: x1 @ w_mlp
    f32x4 C2[12];
#pragma unroll
    for (int nt = 0; nt < 12; ++nt) C2[nt] = (f32x4){0.f, 0.f, 0.f, 0.f};
    for (int kk = 0; kk < 6; ++kk) {
        __syncthreads();
#pragma unroll
        for (int i = 0; i < 6; ++i) {
            int idx = tid + i * 256;
            int kr = idx / 48, g = idx - kr * 48;
            float4 v = *(const float4*)&w_mlp[(size_t)(kk * 32 + kr) * 192 + g * 4];
            Bl[(g * 4 + 0) * 40 + kr] = f2bf(v.x);
            Bl[(g * 4 + 1) * 40 + kr] = f2bf(v.y);
            Bl[(g * 4 + 2) * 40 + kr] = f2bf(v.z);
            Bl[(g * 4 + 3) * 40 + kr] = f2bf(v.w);
        }
        __syncthreads();
        bfrag a = *(const bfrag*)&Al[(w * 16 + li) * 200 + kk * 32 + lg * 8];
#pragma unroll
        for (int nt = 0; nt < 12; ++nt) {
            bfrag b = *(const bfrag*)&Bl[(nt * 16 + li) * 40 + lg * 8];
            C2[nt] = __builtin_amdgcn_mfma_f32_16x16x32_bf16(a, b, C2[nt], 0, 0, 0);
        }
    }

    // LN2 + residual -> out (fp32)
    {
        float bp[12], gg[12], bb[12];
#pragma unroll
        for (int nt = 0; nt < 12; ++nt) {
            int f = nt * 16 + li;
            bp[nt] = b_mlp[f]; gg[nt] = g2[f]; bb[nt] = b2[f];
        }
#pragma unroll
        for (int r = 0; r < 4; ++r) {
            float s1 = 0.f;
#pragma unroll
            for (int nt = 0; nt < 12; ++nt) s1 += C2[nt][r] + bp[nt];
            s1 += __shfl_xor(s1, 1); s1 += __shfl_xor(s1, 2);
            s1 += __shfl_xor(s1, 4); s1 += __shfl_xor(s1, 8);
            float mean = s1 * (1.f / 192.f);
            float s2 = 0.f;
#pragma unroll
            for (int nt = 0; nt < 12; ++nt) {
                float dv = C2[nt][r] + bp[nt] - mean; s2 += dv * dv;
            }
            s2 += __shfl_xor(s2, 1); s2 += __shfl_xor(s2, 2);
            s2 += __shfl_xor(s2, 4); s2 += __shfl_xor(s2, 8);
            float rstd = rsqrtf(s2 * (1.f / 192.f) + 1e-5f);
            int t = t0 + w * 16 + lg * 4 + r;
#pragma unroll
            for (int nt = 0; nt < 12; ++nt) {
                int f = nt * 16 + li;
                float ln = (C2[nt][r] + bp[nt] - mean) * rstd * gg[nt] + bb[nt];
                out[(size_t)t * 192 + f] = C[nt][r] + ln;
            }
        }
    }
}

extern "C" void kernel_launch(void* const* d_in, const int* in_sizes, int n_in,
                              void* d_out, int out_size, void* d_ws, size_t ws_size,
                              hipStream_t stream) {
    const float* x          = (const float*)d_in[0];
    const float* w_qkv      = (const float*)d_in[1];
    const float* b_qkv      = (const float*)d_in[2];
    const float* w_proj     = (const float*)d_in[3];
    const float* b_proj     = (const float*)d_in[4];
    const float* bias_table = (const float*)d_in[5];
    const float* g1         = (const float*)d_in[6];
    const float* b1         = (const float*)d_in[7];
    const float* g2         = (const float*)d_in[8];
    const float* b2         = (const float*)d_in[9];
    const float* w_mlp      = (const float*)d_in[10];
    const float* b_mlp      = (const float*)d_in[11];

    char* ws = (char*)d_ws;
    unsigned short* qkv_ws = (unsigned short*)ws;                   // 159,252,480 B
    unsigned short* bias_r = (unsigned short*)(ws + 159252480);     //  15,925,248 B
    unsigned short* o_ws   = (unsigned short*)(ws + 175177728);     //  53,084,160 B
    // w_qkv_t overlaps the o_ws region: consumed by qkv_mfma before attn writes o.
    unsigned short* w_t    = o_ws;                                  //     221,184 B
    // total ws use: 228,261,888 B (same as round 1)

    wconv<<<432, 256, 0, stream>>>(w_qkv, w_t);
    bias_reorg<<<31104, 256, 0, stream>>>(bias_table, bias_r);
    qkv_mfma<<<2160, 256, 0, stream>>>(x, w_t, b_qkv, qkv_ws);
    attn_mfma<<<dim3(960, 6), 192, 0, stream>>>(qkv_ws, bias_r, o_ws);
    mlp_mfma<<<2160, 256, 0, stream>>>(o_ws, x, w_proj, b_proj, g1, b1, g2, b2,
                                       w_mlp, b_mlp, (float*)d_out);
}

// Round 3
// 407.627 us; speedup vs baseline: 5.5385x; 1.3833x over previous
//
#include <hip/hip_runtime.h>

// EarthSpecificBlock, MI355X round 3: fix mlp weight-staging bank conflicts
// via pre-transposed bf16 weights (wconv2). Other kernels as round 2.

#define QKV_PART 26542080   // 960*6*144*32 elements per q/k/v part

typedef __attribute__((ext_vector_type(8))) short bfrag;          // 8 bf16 (4 VGPR)
typedef __attribute__((ext_vector_type(4))) float f32x4;          // C/D frag
typedef __attribute__((ext_vector_type(4))) unsigned short us4;   // 8B of bf16

__device__ __forceinline__ unsigned short f2bf(float f) {
    unsigned int u = __builtin_bit_cast(unsigned int, f);
    u += 0x7fffu + ((u >> 16) & 1u);        // RNE
    return (unsigned short)(u >> 16);
}
__device__ __forceinline__ float bf2f(unsigned short s) {
    return __builtin_bit_cast(float, ((unsigned int)s) << 16);
}
__device__ __forceinline__ int token_of(int iw, int n) {
    int wi = iw % 15, hi = (iw / 15) % 16, zi = iw / 240;
    int ww = n % 12, hh = (n / 12) % 6, zz = n / 72;
    return ((zi * 2 + zz) * 96 + hi * 6 + hh) * 180 + wi * 12 + ww;
}

// ---- setup: transpose+convert w_qkv [192][576] -> [576][192] bf16 ----
__global__ __launch_bounds__(256) void wconv(const float* __restrict__ w_qkv,
                                             unsigned short* __restrict__ wt) {
    int id = blockIdx.x * 256 + threadIdx.x;       // 110592
    if (id >= 110592) return;
    int k = id / 576, c = id - k * 576;
    wt[c * 192 + k] = f2bf(w_qkv[id]);
}

// ---- setup: transpose+convert w (192x192) -> [n][k] bf16; y=0: w_proj, y=1: w_mlp ----
__global__ __launch_bounds__(256) void wconv2(const float* __restrict__ w_proj,
                                              const float* __restrict__ w_mlp,
                                              unsigned short* __restrict__ wp_t,
                                              unsigned short* __restrict__ wm_t) {
    int id = blockIdx.x * 256 + threadIdx.x;       // 36864
    if (id >= 36864) return;
    const float* src = blockIdx.y ? w_mlp : w_proj;
    unsigned short* dst = blockIdx.y ? wm_t : wp_t;
    int n = id / 192, k = id - n * 192;
    dst[id] = f2bf(src[(size_t)k * 192 + n]);      // coalesced write, gathered read (L2)
}

// ---- bias_r[th][i][j] = bias_table[posidx(i,j)][t][h] (bf16) ----
__global__ __launch_bounds__(256) void bias_reorg(const float* __restrict__ bias_table,
                                                  unsigned short* __restrict__ bias_r) {
    int id = blockIdx.x * 256 + threadIdx.x;       // 144*144*384
    if (id >= 144 * 144 * 384) return;
    int th = id % 384;
    int pair = id / 384;
    int i = pair / 144, j = pair % 144;
    int z1 = i / 72, h1 = (i / 12) % 6, w1 = i % 12;
    int z2 = j / 72, h2 = (j / 12) % 6, w2 = j % 12;
    int idx = (z1 + 2 * z2) * 828 + (h1 + 6 * h2) * 23 + (w1 - w2 + 11);
    bias_r[(size_t)th * 20736 + pair] = f2bf(bias_table[idx * 384 + th]);
}

// ---- QKV GEMM: M=138240 (64/block), N=576, K=192. out [part][iw][h][n][32] bf16 ----
__global__ __launch_bounds__(256) void qkv_mfma(const float* __restrict__ x,
                                                const unsigned short* __restrict__ wt,
                                                const float* __restrict__ b_qkv,
                                                unsigned short* __restrict__ qkv_ws) {
    __shared__ __align__(16) unsigned short As[64 * 40];    //  5120 B, pad-40
    __shared__ __align__(16) unsigned short Bs[576 * 40];   // 46080 B
    int tid = threadIdx.x;
    int m0 = blockIdx.x * 64;
    int w = tid >> 6, l = tid & 63, li = l & 15, lg = l >> 4;

    f32x4 acc[36];
#pragma unroll
    for (int nt = 0; nt < 36; ++nt) acc[nt] = (f32x4){0.f, 0.f, 0.f, 0.f};

    for (int kk = 0; kk < 6; ++kk) {
        __syncthreads();
        // stage A: 64 rows x 32 k (fp32 -> bf16)
#pragma unroll
        for (int i = 0; i < 2; ++i) {
            int idx = tid + i * 256;                 // < 512
            int r = idx >> 3, g = idx & 7;
            float4 v = *(const float4*)&x[(size_t)(m0 + r) * 192 + kk * 32 + g * 4];
            us4 p; p[0] = f2bf(v.x); p[1] = f2bf(v.y); p[2] = f2bf(v.z); p[3] = f2bf(v.w);
            *(us4*)&As[r * 40 + g * 4] = p;
        }
        // stage B: 576 rows x 32 k from wt [576][192]
#pragma unroll
        for (int i = 0; i < 9; ++i) {
            int idx = tid + i * 256;                 // < 2304
            int r = idx >> 2, g = idx & 3;
            *(uint4*)&Bs[r * 40 + g * 8] = *(const uint4*)&wt[(size_t)r * 192 + kk * 32 + g * 8];
        }
        __syncthreads();
        bfrag a = *(const bfrag*)&As[(w * 16 + li) * 40 + lg * 8];
#pragma unroll
        for (int nt = 0; nt < 36; ++nt) {
            bfrag b = *(const bfrag*)&Bs[(nt * 16 + li) * 40 + lg * 8];
            acc[nt] = __builtin_amdgcn_mfma_f32_16x16x32_bf16(a, b, acc[nt], 0, 0, 0);
        }
    }

    // epilogue: token -> (iw, n) bases for this lane's 4 rows
    int base[4];
#pragma unroll
    for (int r = 0; r < 4; ++r) {
        int t = m0 + w * 16 + lg * 4 + r;
        int z = t / 17280; int r1 = t - z * 17280;
        int hh_ = r1 / 180;  int ww_ = r1 - hh_ * 180;
        int zi = z >> 1, zz = z & 1;
        int hi = hh_ / 6, hs = hh_ - hi * 6;
        int wi = ww_ / 12, wsm = ww_ - wi * 12;
        int iw = (zi * 16 + hi) * 15 + wi;
        int n = (zz * 6 + hs) * 12 + wsm;
        base[r] = iw * 27648 + n * 32;
    }
#pragma unroll
    for (int nt = 0; nt < 36; ++nt) {
        int f0 = nt * 16;
        int part = f0 / 192;
        int fr = f0 - part * 192;
        int h = fr >> 5, d0 = fr & 31;
        float bias = b_qkv[f0 + li];
        size_t off = (size_t)part * QKV_PART + h * 4608 + d0 + li;
#pragma unroll
        for (int r = 0; r < 4; ++r)
            qkv_ws[off + base[r]] = f2bf(acc[nt][r] + bias);
    }
}

// ---- Attention: block=(iw,h), 3 waves x 3 query-tiles. S^T = mfma(K,Q). ----
__global__ __launch_bounds__(192) void attn_mfma(const unsigned short* __restrict__ qkv_ws,
                                                 const unsigned short* __restrict__ bias_r,
                                                 unsigned short* __restrict__ o_ws) {
    __shared__ __align__(16) unsigned short Kl[144 * 40];   // 11520 B
    __shared__ __align__(16) unsigned short Ql[144 * 40];   // 11520 B
    __shared__ __align__(16) unsigned short Vt[32 * 168];   // 10752 B (V^T, k-padded to 160)
    __shared__ __align__(16) unsigned short Pb[3][48 * 40]; // 11520 B per-wave P/O buf
    int tid = threadIdx.x;
    int iw = blockIdx.x, h = blockIdx.y;
    int w = tid >> 6, l = tid & 63, li = l & 15, lg = l >> 4;

    const unsigned short* qp = qkv_ws + (size_t)(iw * 6 + h) * 4608;
    const unsigned short* kp = qp + (size_t)QKV_PART;
    const unsigned short* vp = qp + 2 * (size_t)QKV_PART;

    // stage K, Q ([144][40] padded), V transposed ([32][168], cols 144..159 zeroed)
#pragma unroll
    for (int i = 0; i < 3; ++i) {
        int idx = tid + i * 192;                    // exactly 576
        int r = idx >> 2, g = idx & 3;
        *(uint4*)&Kl[r * 40 + g * 8] = *(const uint4*)&kp[r * 32 + g * 8];
        *(uint4*)&Ql[r * 40 + g * 8] = *(const uint4*)&qp[r * 32 + g * 8];
        uint4 v = *(const uint4*)&vp[r * 32 + g * 8];
        unsigned int vv[4] = {v.x, v.y, v.z, v.w};
#pragma unroll
        for (int e = 0; e < 4; ++e) {
            Vt[(g * 8 + 2 * e + 0) * 168 + r] = (unsigned short)(vv[e] & 0xffffu);
            Vt[(g * 8 + 2 * e + 1) * 168 + r] = (unsigned short)(vv[e] >> 16);
        }
    }
    if (tid < 64) {
        int d = tid >> 1, half = tid & 1;
        *(uint4*)&Vt[d * 168 + 144 + half * 8] = (uint4){0u, 0u, 0u, 0u};
    }
    __syncthreads();

    int it0 = w * 3;   // wave's 3 query tiles
    bfrag qf[3];
#pragma unroll
    for (int itl = 0; itl < 3; ++itl)
        qf[itl] = *(const bfrag*)&Ql[((it0 + itl) * 16 + li) * 40 + lg * 8];

    // S^T[j][i] = sum_d K[j][d] Q[i][d]
    f32x4 S[9][3];
#pragma unroll
    for (int jt = 0; jt < 9; ++jt) {
        bfrag kf = *(const bfrag*)&Kl[(jt * 16 + li) * 40 + lg * 8];
#pragma unroll
        for (int itl = 0; itl < 3; ++itl) {
            f32x4 z = (f32x4){0.f, 0.f, 0.f, 0.f};
            S[jt][itl] = __builtin_amdgcn_mfma_f32_16x16x32_bf16(kf, qf[itl], z, 0, 0, 0);
        }
    }

    // scale + bias: lane holds (j = jt*16+lg*4+r, i = (it0+itl)*16+li)
    const unsigned short* bp = bias_r + ((size_t)((iw & 63) * 6 + h)) * 20736;
    const float inv_scale = 0.17677669529663687f;   // 1/sqrt(32)
#pragma unroll
    for (int jt = 0; jt < 9; ++jt) {
#pragma unroll
        for (int itl = 0; itl < 3; ++itl) {
            int i = (it0 + itl) * 16 + li;
            int j0 = jt * 16 + lg * 4;
            us4 bv = *(const us4*)&bp[i * 144 + j0];
#pragma unroll
            for (int r = 0; r < 4; ++r)
                S[jt][itl][r] = S[jt][itl][r] * inv_scale + bf2f(bv[r]);
        }
    }

    // softmax over j (per-lane 36 + shfl_xor 16,32); keep P unnormalized, defer 1/sum
    float inv[3];
#pragma unroll
    for (int itl = 0; itl < 3; ++itl) {
        float mx = -3.0e38f;
#pragma unroll
        for (int jt = 0; jt < 9; ++jt)
#pragma unroll
            for (int r = 0; r < 4; ++r) mx = fmaxf(mx, S[jt][itl][r]);
        mx = fmaxf(mx, __shfl_xor(mx, 16));
        mx = fmaxf(mx, __shfl_xor(mx, 32));
        float sum = 0.f;
#pragma unroll
        for (int jt = 0; jt < 9; ++jt)
#pragma unroll
            for (int r = 0; r < 4; ++r) {
                float e = __expf(S[jt][itl][r] - mx);
                S[jt][itl][r] = e;
                sum += e;
            }
        sum += __shfl_xor(sum, 16);
        sum += __shfl_xor(sum, 32);
        inv[itl] = 1.f / sum;
    }

    // PV: O^T[d][i] += V^T[d][jc*32..] * P^T[jc*32..][i], 5 chunks (j padded to 160)
    f32x4 O[2][3];
#pragma unroll
    for (int dt = 0; dt < 2; ++dt)
#pragma unroll
        for (int itl = 0; itl < 3; ++itl) O[dt][itl] = (f32x4){0.f, 0.f, 0.f, 0.f};

    for (int jc = 0; jc < 5; ++jc) {
#pragma unroll
        for (int itl = 0; itl < 3; ++itl) {
            int irow = itl * 16 + li;
#pragma unroll
            for (int half = 0; half < 2; ++half) {
                int jt = jc * 2 + half;
                us4 pk;
                if (jt < 9) {
                    pk[0] = f2bf(S[jt][itl][0]); pk[1] = f2bf(S[jt][itl][1]);
                    pk[2] = f2bf(S[jt][itl][2]); pk[3] = f2bf(S[jt][itl][3]);
                } else {
                    pk = (us4){0, 0, 0, 0};
                }
                *(us4*)&Pb[w][irow * 40 + half * 16 + lg * 4] = pk;
            }
        }
        bfrag pf[3], af[2];
#pragma unroll
        for (int itl = 0; itl < 3; ++itl)
            pf[itl] = *(const bfrag*)&Pb[w][(itl * 16 + li) * 40 + lg * 8];
#pragma unroll
        for (int dt = 0; dt < 2; ++dt)
            af[dt] = *(const bfrag*)&Vt[(dt * 16 + li) * 168 + jc * 32 + lg * 8];
#pragma unroll
        for (int dt = 0; dt < 2; ++dt)
#pragma unroll
            for (int itl = 0; itl < 3; ++itl)
                O[dt][itl] = __builtin_amdgcn_mfma_f32_16x16x32_bf16(af[dt], pf[itl], O[dt][itl], 0, 0, 0);
    }

    // normalize + transpose via Pb, then coalesced global write (64B per token row)
#pragma unroll
    for (int itl = 0; itl < 3; ++itl) {
#pragma unroll
        for (int dt = 0; dt < 2; ++dt) {
            us4 ov;
            ov[0] = f2bf(O[dt][itl][0] * inv[itl]);
            ov[1] = f2bf(O[dt][itl][1] * inv[itl]);
            ov[2] = f2bf(O[dt][itl][2] * inv[itl]);
            ov[3] = f2bf(O[dt][itl][3] * inv[itl]);
            *(us4*)&Pb[w][(itl * 16 + li) * 40 + dt * 16 + lg * 4] = ov;
        }
    }
#pragma unroll
    for (int s = 0; s < 3; ++s) {
        int gi = s * 64 + l;                  // < 192
        int row = gi >> 2, g = gi & 3;
        uint4 v = *(const uint4*)&Pb[w][row * 40 + g * 8];
        int t = token_of(iw, it0 * 16 + row);
        *(uint4*)&o_ws[(size_t)t * 192 + h * 32 + g * 8] = v;
    }
}

// ---- Fused proj+LN1+res -> mlp+LN2+res. 64 rows/block, MFMA GEMMs. ----
// Weights pre-transposed to bf16 [n][k] (wp_t, wm_t) -> pure uint4 staging.
__global__ __launch_bounds__(256) void mlp_mfma(const unsigned short* __restrict__ o_ws,
                                                const float* __restrict__ x,
                                                const unsigned short* __restrict__ wp_t,
                                                const float* __restrict__ b_proj,
                                                const float* __restrict__ g1,
                                                const float* __restrict__ b1,
                                                const float* __restrict__ g2,
                                                const float* __restrict__ b2,
                                                const unsigned short* __restrict__ wm_t,
                                                const float* __restrict__ b_mlp,
                                                float* __restrict__ out) {
    __shared__ __align__(16) unsigned short Al[64 * 200];   // 25600 B (A1 then x1)
    __shared__ __align__(16) unsigned short Bl[192 * 40];   // 15360 B
    int tid = threadIdx.x;
    int t0 = blockIdx.x * 64;
    int w = tid >> 6, l = tid & 63, li = l & 15, lg = l >> 4;

    // stage A1 = o_ws rows (bf16, full K)
#pragma unroll
    for (int i = 0; i < 6; ++i) {
        int idx = tid + i * 256;                 // < 1536
        int r = idx / 24, g = idx - r * 24;
        *(uint4*)&Al[r * 200 + g * 8] = *(const uint4*)&o_ws[(size_t)(t0 + r) * 192 + g * 8];
    }
    __syncthreads();

    f32x4 C[12];
#pragma unroll
    for (int nt = 0; nt < 12; ++nt) C[nt] = (f32x4){0.f, 0.f, 0.f, 0.f};
    for (int kk = 0; kk < 6; ++kk) {
        __syncthreads();
#pragma unroll
        for (int i = 0; i < 3; ++i) {
            int idx = tid + i * 256;             // < 768
            int r = idx >> 2, g = idx & 3;
            *(uint4*)&Bl[r * 40 + g * 8] = *(const uint4*)&wp_t[(size_t)r * 192 + kk * 32 + g * 8];
        }
        __syncthreads();
        bfrag a = *(const bfrag*)&Al[(w * 16 + li) * 200 + kk * 32 + lg * 8];
#pragma unroll
        for (int nt = 0; nt < 12; ++nt) {
            bfrag b = *(const bfrag*)&Bl[(nt * 16 + li) * 40 + lg * 8];
            C[nt] = __builtin_amdgcn_mfma_f32_16x16x32_bf16(a, b, C[nt], 0, 0, 0);
        }
    }

    // LN1 + residual; C := x1 (f32); write bf16 x1 into Al (own rows only)
    {
        float bp[12], gg[12], bb[12];
#pragma unroll
        for (int nt = 0; nt < 12; ++nt) {
            int f = nt * 16 + li;
            bp[nt] = b_proj[f]; gg[nt] = g1[f]; bb[nt] = b1[f];
        }
#pragma unroll
        for (int r = 0; r < 4; ++r) {
            float s1 = 0.f;
#pragma unroll
            for (int nt = 0; nt < 12; ++nt) s1 += C[nt][r] + bp[nt];
            s1 += __shfl_xor(s1, 1); s1 += __shfl_xor(s1, 2);
            s1 += __shfl_xor(s1, 4); s1 += __shfl_xor(s1, 8);
            float mean = s1 * (1.f / 192.f);
            float s2 = 0.f;
#pragma unroll
            for (int nt = 0; nt < 12; ++nt) {
                float dv = C[nt][r] + bp[nt] - mean; s2 += dv * dv;
            }
            s2 += __shfl_xor(s2, 1); s2 += __shfl_xor(s2, 2);
            s2 += __shfl_xor(s2, 4); s2 += __shfl_xor(s2, 8);
            float rstd = rsqrtf(s2 * (1.f / 192.f) + 1e-5f);
            int row = w * 16 + lg * 4 + r;
            int t = t0 + row;
#pragma unroll
            for (int nt = 0; nt < 12; ++nt) {
                int f = nt * 16 + li;
                float ln = (C[nt][r] + bp[nt] - mean) * rstd * gg[nt] + bb[nt];
                float x1 = x[(size_t)t * 192 + f] + ln;
                C[nt][r] = x1;
                Al[row * 200 + f] = f2bf(x1);
            }
        }
    }

    // GEMM2: x1 @ w_mlp
    f32x4 C2[12];
#pragma unroll
    for (int nt = 0; nt < 12; ++nt) C2[nt] = (f32x4){0.f, 0.f, 0.f, 0.f};
    for (int kk = 0; kk < 6; ++kk) {
        __syncthreads();
#pragma unroll
        for (int i = 0; i < 3; ++i) {
            int idx = tid + i * 256;             // < 768
            int r = idx >> 2, g = idx & 3;
            *(uint4*)&Bl[r * 40 + g * 8] = *(const uint4*)&wm_t[(size_t)r * 192 + kk * 32 + g * 8];
        }
        __syncthreads();
        bfrag a = *(const bfrag*)&Al[(w * 16 + li) * 200 + kk * 32 + lg * 8];
#pragma unroll
        for (int nt = 0; nt < 12; ++nt) {
            bfrag b = *(const bfrag*)&Bl[(nt * 16 + li) * 40 + lg * 8];
            C2[nt] = __builtin_amdgcn_mfma_f32_16x16x32_bf16(a, b, C2[nt], 0, 0, 0);
        }
    }

    // LN2 + residual -> out (fp32)
    {
        float bp[12], gg[12], bb[12];
#pragma unroll
        for (int nt = 0; nt < 12; ++nt) {
            int f = nt * 16 + li;
            bp[nt] = b_mlp[f]; gg[nt] = g2[f]; bb[nt] = b2[f];
        }
#pragma unroll
        for (int r = 0; r < 4; ++r) {
            float s1 = 0.f;
#pragma unroll
            for (int nt = 0; nt < 12; ++nt) s1 += C2[nt][r] + bp[nt];
            s1 += __shfl_xor(s1, 1); s1 += __shfl_xor(s1, 2);
            s1 += __shfl_xor(s1, 4); s1 += __shfl_xor(s1, 8);
            float mean = s1 * (1.f / 192.f);
            float s2 = 0.f;
#pragma unroll
            for (int nt = 0; nt < 12; ++nt) {
                float dv = C2[nt][r] + bp[nt] - mean; s2 += dv * dv;
            }
            s2 += __shfl_xor(s2, 1); s2 += __shfl_xor(s2, 2);
            s2 += __shfl_xor(s2, 4); s2 += __shfl_xor(s2, 8);
            float rstd = rsqrtf(s2 * (1.f / 192.f) + 1e-5f);
            int t = t0 + w * 16 + lg * 4 + r;
#pragma unroll
            for (int nt = 0; nt < 12; ++nt) {
                int f = nt * 16 + li;
                float ln = (C2[nt][r] + bp[nt] - mean) * rstd * gg[nt] + bb[nt];
                out[(size_t)t * 192 + f] = C[nt][r] + ln;
            }
        }
    }
}

extern "C" void kernel_launch(void* const* d_in, const int* in_sizes, int n_in,
                              void* d_out, int out_size, void* d_ws, size_t ws_size,
                              hipStream_t stream) {
    const float* x          = (const float*)d_in[0];
    const float* w_qkv      = (const float*)d_in[1];
    const float* b_qkv      = (const float*)d_in[2];
    const float* w_proj     = (const float*)d_in[3];
    const float* b_proj     = (const float*)d_in[4];
    const float* bias_table = (const float*)d_in[5];
    const float* g1         = (const float*)d_in[6];
    const float* b1         = (const float*)d_in[7];
    const float* g2         = (const float*)d_in[8];
    const float* b2         = (const float*)d_in[9];
    const float* w_mlp      = (const float*)d_in[10];
    const float* b_mlp      = (const float*)d_in[11];

    char* ws = (char*)d_ws;
    unsigned short* qkv_ws = (unsigned short*)ws;                   // 159,252,480 B
    unsigned short* bias_r = (unsigned short*)(ws + 159252480);     //  15,925,248 B
    unsigned short* o_ws   = (unsigned short*)(ws + 175177728);     //  53,084,160 B
    // w_qkv_t overlaps o_ws: consumed by qkv_mfma before attn writes o_ws.
    unsigned short* w_t    = o_ws;                                  //     221,184 B
    // wp_t/wm_t overlap qkv_ws: written AFTER attn (stream order), read by mlp.
    unsigned short* wp_t   = qkv_ws;                                //     147,456 B
    unsigned short* wm_t   = qkv_ws + 73728;                        //     147,456 B
    // total ws use: 228,261,888 B (same as rounds 1-2)

    wconv<<<432, 256, 0, stream>>>(w_qkv, w_t);
    bias_reorg<<<31104, 256, 0, stream>>>(bias_table, bias_r);
    qkv_mfma<<<2160, 256, 0, stream>>>(x, w_t, b_qkv, qkv_ws);
    attn_mfma<<<dim3(960, 6), 192, 0, stream>>>(qkv_ws, bias_r, o_ws);
    wconv2<<<dim3(144, 2), 256, 0, stream>>>(w_proj, w_mlp, wp_t, wm_t);
    mlp_mfma<<<2160, 256, 0, stream>>>(o_ws, x, wp_t, b_proj, g1, b1, g2, b2,
                                       wm_t, b_mlp, (float*)d_out);
}